// Round 6
// baseline (327.291 us; speedup 1.0000x reference)
//
#include <hip/hip_runtime.h>
#include <math.h>

#define DIMC 256
#define NHEADS 8
#define HDIM 32
#define CPBH 512
#define BB 2
#define NSEQ 2304
#define TAB 9025
#define RTOT (BB*NHEADS*NSEQ)      // 36864
#define SPLITS 4
#define MSP (NSEQ/SPLITS)          // 576 m per split
#define PBS 36                     // pbuf row stride in u16
#define NCHUNK (NSEQ/32)           // 72

#define NX  (BB*NSEQ*DIMC)         // 1,179,648
#define NWQ (3*DIMC*DIMC)          // 196,608
#define NWP (DIMC*DIMC)            // 65,536

#define SPLIT_BLOCKS ((NX + NWQ + NWP) / 256)          // 5632
#define IDXP_ELEMS   (NSEQ * NCHUNK * 16)              // 2,654,208
#define IDXP_BLOCKS  (IDXP_ELEMS / 256)                // 10368
#define CPB_BLOCKS   ((TAB + 63) / 64)                 // 142

typedef unsigned short ushort;
typedef __attribute__((ext_vector_type(8))) short short8;
typedef __attribute__((ext_vector_type(4))) short short4v;
typedef __attribute__((ext_vector_type(4))) float f32x4;

#define MFMA16(a,b,c) __builtin_amdgcn_mfma_f32_16x16x32_bf16((a),(b),(c),0,0,0)

__device__ __forceinline__ ushort f2bf(float x) {          // RNE fp32->bf16
  unsigned u = __float_as_uint(x);
  u += 0x7FFFu + ((u >> 16) & 1u);
  return (ushort)(u >> 16);
}
__device__ __forceinline__ float bf2f(ushort b) {
  return __uint_as_float(((unsigned)b) << 16);
}

// ---------------- setup: split planes + idx pair-pack + CPB MLP, one launch ----------------
__global__ void setup_kernel(const float* __restrict__ x, const float* __restrict__ wq,
                             const float* __restrict__ wp, const int* __restrict__ idx,
                             const float* __restrict__ tbl, const float* __restrict__ W1,
                             const float* __restrict__ b1, const float* __restrict__ W2,
                             const float* __restrict__ b2,
                             ushort* __restrict__ xh, ushort* __restrict__ xl,
                             ushort* __restrict__ wqh, ushort* __restrict__ wql,
                             ushort* __restrict__ wph, ushort* __restrict__ wpl,
                             unsigned* __restrict__ idxP, ushort* __restrict__ tabBf) {
  __shared__ float part[4][64][NHEADS];
  int blk = blockIdx.x;
  int tid = threadIdx.x;
  if (blk < SPLIT_BLOCKS) {
    int i = blk * 256 + tid;
    const float* src; ushort *hi, *lo; int j;
    if (i < NX)            { src = x;  hi = xh;  lo = xl;  j = i; }
    else if (i < NX + NWQ) { src = wq; hi = wqh; lo = wql; j = i - NX; }
    else                   { src = wp; hi = wph; lo = wpl; j = i - NX - NWQ; }
    float v = src[j];
    ushort h = f2bf(v);
    hi[j] = h;
    lo[j] = f2bf(v - bf2f(h));
  } else if (blk < SPLIT_BLOCKS + IDXP_BLOCKS) {
    int e = (blk - SPLIT_BLOCKS) * 256 + tid;
    int cc = e & 15; int ch = (e >> 4) % NCHUNK; int n = e / (16 * NCHUNK);
    int mbase = ch * 32 + cc;
    unsigned lo = (unsigned)idx[(size_t)n * NSEQ + mbase];
    unsigned hi = (unsigned)idx[(size_t)n * NSEQ + mbase + 16];
    idxP[e] = lo | (hi << 16);
  } else {
    int cb = blk - SPLIT_BLOCKS - IDXP_BLOCKS;
    int tl = tid & 63, jc = tid >> 6;                 // 4 j-chunks of 128
    int t = cb * 64 + tl;
    bool valid = t < TAB;
    float c0 = 0.f, c1 = 0.f;
    if (valid) { c0 = tbl[2*t]; c1 = tbl[2*t+1]; }
    float acc[NHEADS];
#pragma unroll
    for (int h = 0; h < NHEADS; ++h) acc[h] = 0.f;
    for (int j = jc * 128; j < jc * 128 + 128; ++j) {
      float hid = fmaxf(fmaf(c0, W1[2*j], fmaf(c1, W1[2*j+1], b1[j])), 0.f);
#pragma unroll
      for (int h = 0; h < NHEADS; ++h) acc[h] = fmaf(hid, W2[h*CPBH + j], acc[h]);
    }
#pragma unroll
    for (int h = 0; h < NHEADS; ++h) part[jc][tl][h] = acc[h];
    __syncthreads();
    if (jc == 0 && valid) {
#pragma unroll
      for (int h = 0; h < NHEADS; ++h) {
        float s = part[0][tl][h] + part[1][tl][h] + part[2][tl][h] + part[3][tl][h] + b2[h];
        tabBf[h*TAB + t] = f2bf(s);
      }
    }
  }
}

// ------- fused QKV GEMM + norm/scale/split + V transpose: writes q/k planes and vT -------
__launch_bounds__(256)
__global__ void gemm_qkv(const ushort* __restrict__ Ah, const ushort* __restrict__ Al,
                         const ushort* __restrict__ Bh, const ushort* __restrict__ Bl,
                         const float* __restrict__ bias, const float* __restrict__ temp,
                         const float* __restrict__ sls, const float* __restrict__ qe,
                         ushort* __restrict__ qhi, ushort* __restrict__ qlo,
                         ushort* __restrict__ khi, ushort* __restrict__ klo,
                         ushort* __restrict__ vT) {
  __shared__ float vbuf[64][65];
  int tid = threadIdx.x;
  int lane = tid & 63, w = tid >> 6;
  int g = lane >> 4, c = lane & 15;
  int n0 = blockIdx.x * 64, m0 = blockIdx.y * 64;
  int mw = m0 + w * 16;
  const int K = DIMC;
  f32x4 acc[4] = {{0,0,0,0},{0,0,0,0},{0,0,0,0},{0,0,0,0}};
#pragma unroll 2
  for (int k0 = 0; k0 < K; k0 += 32) {
    short8 ah = *(const short8*)&Ah[(size_t)(mw + c) * K + k0 + g * 8];
    short8 al = *(const short8*)&Al[(size_t)(mw + c) * K + k0 + g * 8];
#pragma unroll
    for (int nt = 0; nt < 4; ++nt) {
      short8 bh = *(const short8*)&Bh[(size_t)(n0 + nt * 16 + c) * K + k0 + g * 8];
      short8 bl = *(const short8*)&Bl[(size_t)(n0 + nt * 16 + c) * K + k0 + g * 8];
      acc[nt] = MFMA16(ah, bh, acc[nt]);
      acc[nt] = MFMA16(al, bh, acc[nt]);
      acc[nt] = MFMA16(ah, bl, acc[nt]);
    }
  }
#pragma unroll
  for (int nt = 0; nt < 4; ++nt) {
    float bv = bias[n0 + nt * 16 + c];
#pragma unroll
    for (int r = 0; r < 4; ++r) acc[nt][r] += bv;
  }

  int b = (m0 >= NSEQ) ? 1 : 0;
  int nb = m0 - b * NSEQ;           // token base within batch
  int sect = n0 >> 8;               // 0=q, 1=k, 2=v

  if (sect < 2) {
    int hloc = (n0 & 255) >> 5;     // 0,2,4,6
#pragma unroll
    for (int H = 0; H < 2; ++H) {
      int head = hloc + H;
#pragma unroll
      for (int r = 0; r < 4; ++r) {
        float ss = acc[2*H][r]*acc[2*H][r] + acc[2*H+1][r]*acc[2*H+1][r];
        ss += __shfl_xor(ss, 1);
        ss += __shfl_xor(ss, 2);
        ss += __shfl_xor(ss, 4);
        ss += __shfl_xor(ss, 8);
        float inv = 1.f / fmaxf(sqrtf(ss), 1e-12f);
        int n = nb + w * 16 + g * 4 + r;
        size_t orow = ((size_t)(b * NHEADS + head) * NSEQ + n) * HDIM;
#pragma unroll
        for (int half = 0; half < 2; ++half) {
          int nt = 2*H + half;
          int d = half * 16 + c;
          float val = acc[nt][r] * inv;
          if (sect == 0) {
            float scale = log1pf(expf(temp[head])) * sls[0];
            val = (val + qe[head * HDIM + d]) * scale;
            ushort hh = f2bf(val);
            qhi[orow + d] = hh;
            qlo[orow + d] = f2bf(val - bf2f(hh));
          } else {
            ushort hh = f2bf(val);
            khi[orow + d] = hh;
            klo[orow + d] = f2bf(val - bf2f(hh));
          }
        }
      }
    }
  } else {
    // V: stage to LDS, transposed + pair-permuted coalesced write
#pragma unroll
    for (int nt = 0; nt < 4; ++nt)
#pragma unroll
      for (int r = 0; r < 4; ++r)
        vbuf[w * 16 + g * 4 + r][nt * 16 + c] = acc[nt][r];
    __syncthreads();
    int hbase = (n0 - 512) >> 5;    // 0,2,4,6
#pragma unroll
    for (int it = 0; it < 16; ++it) {
      int dloc = (tid >> 6) * 16 + it;   // 0..63
      int p = tid & 63;
      int pp = p & 31;
      int nsrc = (p & 32) + (pp & 1) * 16 + (pp >> 1);  // inverse pair-interleave
      float v = vbuf[nsrc][dloc];
      int head = hbase + (dloc >> 5), d = dloc & 31;
      vT[((size_t)((b * NHEADS + head) * HDIM + d)) * NSEQ + nb + p] = f2bf(v);
    }
  }
}

// ------- MFMA flash attention: software-pipelined, no-max softmax, packed idx -------
__launch_bounds__(256)
__global__ void attn_kernel(const ushort* __restrict__ qhi, const ushort* __restrict__ qlo,
                            const ushort* __restrict__ khi, const ushort* __restrict__ klo,
                            const ushort* __restrict__ vT, const ushort* __restrict__ tabBf,
                            const unsigned* __restrict__ idxP,
                            float* __restrict__ pO, float* __restrict__ pL) {
  __shared__ __align__(16) ushort pbuf[4][16 * PBS];
  __shared__ ushort tbf[TAB + 3];
  int tid = threadIdx.x;
  int lane = tid & 63;
  int w = tid >> 6;
  int qb = blockIdx.x;
  int by = blockIdx.y;
  int s = by & 3, bh = by >> 2;
  int h = bh & (NHEADS - 1);

  for (int t = tid; t < TAB; t += 256) tbf[t] = tabBf[h * TAB + t];

  int g = lane >> 4, c = lane & 15;
  int q0 = qb * 64 + w * 16;
  size_t rowbase = (size_t)bh * NSEQ;

  short8 qh = *(const short8*)&qhi[(rowbase + q0 + c) * HDIM + g * 8];
  short8 ql = *(const short8*)&qlo[(rowbase + q0 + c) * HDIM + g * 8];
  __syncthreads();

  float Lp[4] = {0.f, 0.f, 0.f, 0.f};
  f32x4 o0 = {0.f, 0.f, 0.f, 0.f}, o1 = {0.f, 0.f, 0.f, 0.f};
  ushort* pb = pbuf[w];
  int m0 = s * MSP;

#define LOADK(MT, D0H, D0L, D1H, D1L, I0, I1, I2, I3) do {            \
    size_t ra_ = (rowbase + (MT) + c) * HDIM + g * 8;                 \
    D0H = *(const short8*)&khi[ra_];                                  \
    D0L = *(const short8*)&klo[ra_];                                  \
    D1H = *(const short8*)&khi[ra_ + 16 * HDIM];                      \
    D1L = *(const short8*)&klo[ra_ + 16 * HDIM];                      \
    size_t ib_ = ((size_t)(q0 + g * 4) * NCHUNK + ((MT) >> 5)) * 16 + c; \
    I0 = idxP[ib_];                                                   \
    I1 = idxP[ib_ + (size_t)NCHUNK * 16];                             \
    I2 = idxP[ib_ + (size_t)2 * NCHUNK * 16];                         \
    I3 = idxP[ib_ + (size_t)3 * NCHUNK * 16];                         \
  } while (0)

  short8 c0h, c0l, c1h, c1l;
  unsigned ip0, ip1, ip2, ip3;
  LOADK(m0, c0h, c0l, c1h, c1l, ip0, ip1, ip2, ip3);

  for (int mt = m0; mt < m0 + MSP; mt += 32) {
    int mtn = (mt + 32 < m0 + MSP) ? (mt + 32) : m0;
    short8 n0h, n0l, n1h, n1l;
    unsigned jp0, jp1, jp2, jp3;
    LOADK(mtn, n0h, n0l, n1h, n1l, jp0, jp1, jp2, jp3);   // prefetch next

    f32x4 s0 = {0.f, 0.f, 0.f, 0.f}, s1 = {0.f, 0.f, 0.f, 0.f};
    s0 = MFMA16(qh, c0h, s0);
    s1 = MFMA16(qh, c1h, s1);
    s0 = MFMA16(ql, c0h, s0);
    s1 = MFMA16(ql, c1h, s1);
    s0 = MFMA16(qh, c0l, s0);
    s1 = MFMA16(qh, c1l, s1);

    size_t va = ((size_t)(bh * HDIM + c)) * NSEQ + mt + g * 8;   // vT loads early
    short8 vf0 = *(const short8*)&vT[va];
    short8 vf1 = *(const short8*)&vT[va + 16 * NSEQ];

    unsigned ipr[4] = {ip0, ip1, ip2, ip3};
#pragma unroll
    for (int r = 0; r < 4; ++r) {
      int i0 = ipr[r] & 0xFFFF, i1 = ipr[r] >> 16;
      float p0 = __expf(s0[r] + bf2f(tbf[i0]));
      float p1 = __expf(s1[r] + bf2f(tbf[i1]));
      Lp[r] += p0 + p1;
      unsigned pk = (unsigned)f2bf(p0) | ((unsigned)f2bf(p1) << 16);
      *(unsigned*)&pb[(g * 4 + r) * PBS + 2 * c] = pk;
    }

    short4v pa = *(const short4v*)&pb[c * PBS + g * 8];
    short4v pbv = *(const short4v*)&pb[c * PBS + g * 8 + 4];
    short8 pf = __builtin_shufflevector(pa, pbv, 0, 1, 2, 3, 4, 5, 6, 7);

    o0 = MFMA16(pf, vf0, o0);
    o1 = MFMA16(pf, vf1, o1);

    c0h = n0h; c0l = n0l; c1h = n1h; c1l = n1l;
    ip0 = jp0; ip1 = jp1; ip2 = jp2; ip3 = jp3;
  }
#undef LOADK

#pragma unroll
  for (int r = 0; r < 4; ++r) {
    float l = Lp[r];
    l += __shfl_xor(l, 1);
    l += __shfl_xor(l, 2);
    l += __shfl_xor(l, 4);
    l += __shfl_xor(l, 8);
    Lp[r] = l;
  }
  size_t prow0 = (size_t)s * RTOT + rowbase + q0;
#pragma unroll
  for (int r = 0; r < 4; ++r) {
    size_t pr = prow0 + g * 4 + r;
    pO[pr * HDIM + c]      = o0[r];
    pO[pr * HDIM + 16 + c] = o1[r];
    if (c == 0) pL[pr] = Lp[r];
  }
}

// ------- merge splits (coalesced: lane = channel), emit split-bf16 ao -------
__global__ void merge_kernel(const float* __restrict__ pO, const float* __restrict__ pL,
                             ushort* __restrict__ aoh, ushort* __restrict__ aol) {
  int t = threadIdx.x;
  int r = blockIdx.x * 8 + (t >> 5);
  int i = t & 31;
  float L = 0.f;
#pragma unroll
  for (int sp = 0; sp < SPLITS; ++sp) L += pL[(size_t)sp * RTOT + r];
  float inv = 1.f / L;
  float acc = 0.f;
#pragma unroll
  for (int sp = 0; sp < SPLITS; ++sp) acc += pO[((size_t)sp * RTOT + r) * HDIM + i];
  float v = acc * inv;
  int n = r % NSEQ; int bh = r / NSEQ; int h = bh & (NHEADS - 1); int b = bh >> 3;
  size_t dst = (size_t)(b * NSEQ + n) * DIMC + h * HDIM + i;
  ushort hh = f2bf(v);
  aoh[dst] = hh;
  aol[dst] = f2bf(v - bf2f(hh));
}

// ------- split-bf16 MFMA GEMM (proj): C[M,Nn] = A@W^T + bias -------
__launch_bounds__(256)
__global__ void gemm_mfma(const ushort* __restrict__ Ah, const ushort* __restrict__ Al,
                          const ushort* __restrict__ Bh, const ushort* __restrict__ Bl,
                          const float* __restrict__ bias, float* __restrict__ C,
                          int Nn, int K) {
  int tid = threadIdx.x;
  int lane = tid & 63;
  int w = tid >> 6;
  int g = lane >> 4, c = lane & 15;
  int n0 = blockIdx.x * 64;
  int m0 = blockIdx.y * 64 + w * 16;
  f32x4 acc[4] = {{0,0,0,0},{0,0,0,0},{0,0,0,0},{0,0,0,0}};
#pragma unroll 2
  for (int k0 = 0; k0 < K; k0 += 32) {
    short8 ah = *(const short8*)&Ah[(size_t)(m0 + c) * K + k0 + g * 8];
    short8 al = *(const short8*)&Al[(size_t)(m0 + c) * K + k0 + g * 8];
#pragma unroll
    for (int nt = 0; nt < 4; ++nt) {
      short8 bh = *(const short8*)&Bh[(size_t)(n0 + nt * 16 + c) * K + k0 + g * 8];
      short8 bl = *(const short8*)&Bl[(size_t)(n0 + nt * 16 + c) * K + k0 + g * 8];
      acc[nt] = MFMA16(ah, bh, acc[nt]);
      acc[nt] = MFMA16(al, bh, acc[nt]);
      acc[nt] = MFMA16(ah, bl, acc[nt]);
    }
  }
#pragma unroll
  for (int nt = 0; nt < 4; ++nt) {
    float bv = bias[n0 + nt * 16 + c];
#pragma unroll
    for (int r = 0; r < 4; ++r) {
      C[(size_t)(m0 + g * 4 + r) * Nn + n0 + nt * 16 + c] = acc[nt][r] + bv;
    }
  }
}

extern "C" void kernel_launch(void* const* d_in, const int* in_sizes, int n_in,
                              void* d_out, int out_size, void* d_ws, size_t ws_size,
                              hipStream_t stream) {
  const float* x    = (const float*)d_in[0];
  const int*   idx  = (const int*)d_in[1];
  const float* tbl  = (const float*)d_in[2];
  const float* sls  = (const float*)d_in[3];
  const float* Wqkv = (const float*)d_in[5];
  const float* bqkv = (const float*)d_in[6];
  const float* temp = (const float*)d_in[7];
  const float* qe   = (const float*)d_in[8];
  const float* Wp   = (const float*)d_in[9];
  const float* bp   = (const float*)d_in[10];
  const float* W1   = (const float*)d_in[11];
  const float* b1   = (const float*)d_in[12];
  const float* W2   = (const float*)d_in[13];
  const float* b2   = (const float*)d_in[14];

  float* ws   = (float*)d_ws;
  float* pO   = ws;                        // 4,718,592 f
  float* pL   = pO + 4718592;              // 147,456 f
  unsigned* idxP = (unsigned*)(pL + 147456);   // 2,654,208 u32
  ushort* u   = (ushort*)(idxP + IDXP_ELEMS);
  ushort* qhi = u;                u += (size_t)RTOT * HDIM;
  ushort* qlo = u;                u += (size_t)RTOT * HDIM;
  ushort* khi = u;                u += (size_t)RTOT * HDIM;
  ushort* klo = u;                u += (size_t)RTOT * HDIM;
  ushort* vT  = u;                u += (size_t)RTOT * HDIM;
  ushort* xh  = u;                u += NX;
  ushort* xl  = u;                u += NX;
  ushort* wqh = u;                u += NWQ;
  ushort* wql = u;                u += NWQ;
  ushort* wph = u;                u += NWP;
  ushort* wpl = u;                u += NWP;
  ushort* aoh = u;                u += (size_t)RTOT * HDIM;
  ushort* aol = u;                u += (size_t)RTOT * HDIM;
  ushort* tabBf = u;              u += 72256;   // NHEADS*TAB = 72,200
  float* out  = (float*)d_out;

  setup_kernel<<<dim3(SPLIT_BLOCKS + IDXP_BLOCKS + CPB_BLOCKS), dim3(256), 0, stream>>>(
      x, Wqkv, Wp, idx, tbl, W1, b1, W2, b2,
      xh, xl, wqh, wql, wph, wpl, idxP, tabBf);
  gemm_qkv<<<dim3(12, 72), dim3(256), 0, stream>>>(
      xh, xl, wqh, wql, bqkv, temp, sls, qe, qhi, qlo, khi, klo, vT);
  attn_kernel<<<dim3(NSEQ / 64, BB * NHEADS * SPLITS), dim3(256), 0, stream>>>(
      qhi, qlo, khi, klo, vT, tabBf, idxP, pO, pL);
  merge_kernel<<<dim3(RTOT / 8), dim3(256), 0, stream>>>(pO, pL, aoh, aol);
  gemm_mfma<<<dim3(4, 72), dim3(256), 0, stream>>>(aoh, aol, wph, wpl, bp, out, DIMC, DIMC);
}

// Round 7
// 261.158 us; speedup vs baseline: 1.2532x; 1.2532x over previous
//
#include <hip/hip_runtime.h>
#include <math.h>

#define DIMC 256
#define NHEADS 8
#define HDIM 32
#define CPBH 512
#define BB 2
#define NSEQ 2304
#define TAB 9025
#define RTOT (BB*NHEADS*NSEQ)      // 36864
#define SPLITS 4
#define MSP (NSEQ/SPLITS)          // 576 m per split
#define PBS 36                     // pbuf row stride in u16
#define NCHUNK (NSEQ/32)           // 72

#define NX  (BB*NSEQ*DIMC)         // 1,179,648
#define NWQ (3*DIMC*DIMC)          // 196,608
#define NWP (DIMC*DIMC)            // 65,536

#define SPLIT_BLOCKS ((NX + NWQ + NWP) / 256)          // 5632
#define IDXP_ELEMS   (NSEQ * NCHUNK * 16)              // 2,654,208
#define IDXP_BLOCKS  (IDXP_ELEMS / 256)                // 10368
#define CPB_BLOCKS   ((TAB + 63) / 64)                 // 142

typedef unsigned short ushort;
typedef __attribute__((ext_vector_type(8))) short short8;
typedef __attribute__((ext_vector_type(4))) short short4v;
typedef __attribute__((ext_vector_type(4))) float f32x4;

#define MFMA16(a,b,c) __builtin_amdgcn_mfma_f32_16x16x32_bf16((a),(b),(c),0,0,0)

__device__ __forceinline__ ushort f2bf(float x) {          // RNE fp32->bf16
  unsigned u = __float_as_uint(x);
  u += 0x7FFFu + ((u >> 16) & 1u);
  return (ushort)(u >> 16);
}
__device__ __forceinline__ float bf2f(ushort b) {
  return __uint_as_float(((unsigned)b) << 16);
}

// ------- setup: CPB MLP (LDS-tiled, blocks FIRST) + split planes + idx pair-pack -------
__global__ void setup_kernel(const float* __restrict__ x, const float* __restrict__ wq,
                             const float* __restrict__ wp, const int* __restrict__ idx,
                             const float* __restrict__ tbl, const float* __restrict__ W1,
                             const float* __restrict__ b1, const float* __restrict__ W2,
                             const float* __restrict__ b2,
                             ushort* __restrict__ xh, ushort* __restrict__ xl,
                             ushort* __restrict__ wqh, ushort* __restrict__ wql,
                             ushort* __restrict__ wph, ushort* __restrict__ wpl,
                             unsigned* __restrict__ idxP, ushort* __restrict__ tabBf) {
  __shared__ float w1b[CPBH * 4];            // {W1[2j], W1[2j+1], b1[j], 0}  8 KB
  __shared__ float w2t[CPBH * NHEADS];       // [j][h]                       16 KB
  __shared__ float part[4][64][NHEADS];      //                               8 KB
  int blk = blockIdx.x;
  int tid = threadIdx.x;
  if (blk < CPB_BLOCKS) {
    // ---- CPB: hidden-layer MLP for the bias table, all weights in LDS ----
    for (int i = tid; i < CPBH; i += 256) {
      w1b[i * 4 + 0] = W1[2 * i];
      w1b[i * 4 + 1] = W1[2 * i + 1];
      w1b[i * 4 + 2] = b1[i];
      w1b[i * 4 + 3] = 0.f;
    }
    for (int i = tid; i < CPBH * NHEADS; i += 256)
      w2t[(i & (CPBH - 1)) * NHEADS + (i >> 9)] = W2[i];   // transpose to [j][h]
    int tl = tid & 63, jc = tid >> 6;
    int t = blk * 64 + tl;
    bool valid = t < TAB;
    float c0 = 0.f, c1 = 0.f;
    if (valid) { c0 = tbl[2 * t]; c1 = tbl[2 * t + 1]; }
    __syncthreads();
    float acc[NHEADS];
#pragma unroll
    for (int h = 0; h < NHEADS; ++h) acc[h] = 0.f;
    for (int j = jc * 128; j < jc * 128 + 128; ++j) {   // LDS broadcasts, conflict-free
      float4 wv = *(const float4*)&w1b[j * 4];
      float hid = fmaxf(fmaf(c0, wv.x, fmaf(c1, wv.y, wv.z)), 0.f);
      float4 wa = *(const float4*)&w2t[j * NHEADS];
      float4 wb = *(const float4*)&w2t[j * NHEADS + 4];
      acc[0] = fmaf(hid, wa.x, acc[0]);
      acc[1] = fmaf(hid, wa.y, acc[1]);
      acc[2] = fmaf(hid, wa.z, acc[2]);
      acc[3] = fmaf(hid, wa.w, acc[3]);
      acc[4] = fmaf(hid, wb.x, acc[4]);
      acc[5] = fmaf(hid, wb.y, acc[5]);
      acc[6] = fmaf(hid, wb.z, acc[6]);
      acc[7] = fmaf(hid, wb.w, acc[7]);
    }
#pragma unroll
    for (int h = 0; h < NHEADS; ++h) part[jc][tl][h] = acc[h];
    __syncthreads();
    if (jc == 0 && valid) {
#pragma unroll
      for (int h = 0; h < NHEADS; ++h) {
        float s = part[0][tl][h] + part[1][tl][h] + part[2][tl][h] + part[3][tl][h] + b2[h];
        tabBf[h * TAB + t] = f2bf(s);
      }
    }
  } else if (blk < CPB_BLOCKS + SPLIT_BLOCKS) {
    int i = (blk - CPB_BLOCKS) * 256 + tid;
    const float* src; ushort *hi, *lo; int j;
    if (i < NX)            { src = x;  hi = xh;  lo = xl;  j = i; }
    else if (i < NX + NWQ) { src = wq; hi = wqh; lo = wql; j = i - NX; }
    else                   { src = wp; hi = wph; lo = wpl; j = i - NX - NWQ; }
    float v = src[j];
    ushort h = f2bf(v);
    hi[j] = h;
    lo[j] = f2bf(v - bf2f(h));
  } else {
    int e = (blk - CPB_BLOCKS - SPLIT_BLOCKS) * 256 + tid;
    int cc = e & 15; int ch = (e >> 4) % NCHUNK; int n = e / (16 * NCHUNK);
    int mbase = ch * 32 + cc;
    unsigned lo = (unsigned)idx[(size_t)n * NSEQ + mbase];
    unsigned hi = (unsigned)idx[(size_t)n * NSEQ + mbase + 16];
    idxP[e] = lo | (hi << 16);
  }
}

// ------- fused QKV GEMM + norm/scale/split + V transpose: writes q/k planes and vT -------
__launch_bounds__(256)
__global__ void gemm_qkv(const ushort* __restrict__ Ah, const ushort* __restrict__ Al,
                         const ushort* __restrict__ Bh, const ushort* __restrict__ Bl,
                         const float* __restrict__ bias, const float* __restrict__ temp,
                         const float* __restrict__ sls, const float* __restrict__ qe,
                         ushort* __restrict__ qhi, ushort* __restrict__ qlo,
                         ushort* __restrict__ khi, ushort* __restrict__ klo,
                         ushort* __restrict__ vT) {
  __shared__ float vbuf[64][65];
  int tid = threadIdx.x;
  int lane = tid & 63, w = tid >> 6;
  int g = lane >> 4, c = lane & 15;
  int n0 = blockIdx.x * 64, m0 = blockIdx.y * 64;
  int mw = m0 + w * 16;
  const int K = DIMC;
  f32x4 acc[4] = {{0,0,0,0},{0,0,0,0},{0,0,0,0},{0,0,0,0}};
#pragma unroll 2
  for (int k0 = 0; k0 < K; k0 += 32) {
    short8 ah = *(const short8*)&Ah[(size_t)(mw + c) * K + k0 + g * 8];
    short8 al = *(const short8*)&Al[(size_t)(mw + c) * K + k0 + g * 8];
#pragma unroll
    for (int nt = 0; nt < 4; ++nt) {
      short8 bh = *(const short8*)&Bh[(size_t)(n0 + nt * 16 + c) * K + k0 + g * 8];
      short8 bl = *(const short8*)&Bl[(size_t)(n0 + nt * 16 + c) * K + k0 + g * 8];
      acc[nt] = MFMA16(ah, bh, acc[nt]);
      acc[nt] = MFMA16(al, bh, acc[nt]);
      acc[nt] = MFMA16(ah, bl, acc[nt]);
    }
  }
#pragma unroll
  for (int nt = 0; nt < 4; ++nt) {
    float bv = bias[n0 + nt * 16 + c];
#pragma unroll
    for (int r = 0; r < 4; ++r) acc[nt][r] += bv;
  }

  int b = (m0 >= NSEQ) ? 1 : 0;
  int nb = m0 - b * NSEQ;           // token base within batch
  int sect = n0 >> 8;               // 0=q, 1=k, 2=v

  if (sect < 2) {
    int hloc = (n0 & 255) >> 5;     // 0,2,4,6
#pragma unroll
    for (int H = 0; H < 2; ++H) {
      int head = hloc + H;
#pragma unroll
      for (int r = 0; r < 4; ++r) {
        float ss = acc[2*H][r]*acc[2*H][r] + acc[2*H+1][r]*acc[2*H+1][r];
        ss += __shfl_xor(ss, 1);
        ss += __shfl_xor(ss, 2);
        ss += __shfl_xor(ss, 4);
        ss += __shfl_xor(ss, 8);
        float inv = 1.f / fmaxf(sqrtf(ss), 1e-12f);
        int n = nb + w * 16 + g * 4 + r;
        size_t orow = ((size_t)(b * NHEADS + head) * NSEQ + n) * HDIM;
#pragma unroll
        for (int half = 0; half < 2; ++half) {
          int nt = 2*H + half;
          int d = half * 16 + c;
          float val = acc[nt][r] * inv;
          if (sect == 0) {
            float scale = log1pf(expf(temp[head])) * sls[0];
            val = (val + qe[head * HDIM + d]) * scale;
            ushort hh = f2bf(val);
            qhi[orow + d] = hh;
            qlo[orow + d] = f2bf(val - bf2f(hh));
          } else {
            ushort hh = f2bf(val);
            khi[orow + d] = hh;
            klo[orow + d] = f2bf(val - bf2f(hh));
          }
        }
      }
    }
  } else {
    // V: stage to LDS, transposed + pair-permuted coalesced write
#pragma unroll
    for (int nt = 0; nt < 4; ++nt)
#pragma unroll
      for (int r = 0; r < 4; ++r)
        vbuf[w * 16 + g * 4 + r][nt * 16 + c] = acc[nt][r];
    __syncthreads();
    int hbase = (n0 - 512) >> 5;    // 0,2,4,6
#pragma unroll
    for (int it = 0; it < 16; ++it) {
      int dloc = (tid >> 6) * 16 + it;   // 0..63
      int p = tid & 63;
      int pp = p & 31;
      int nsrc = (p & 32) + (pp & 1) * 16 + (pp >> 1);  // inverse pair-interleave
      float v = vbuf[nsrc][dloc];
      int head = hbase + (dloc >> 5), d = dloc & 31;
      vT[((size_t)((b * NHEADS + head) * HDIM + d)) * NSEQ + nb + p] = f2bf(v);
    }
  }
}

// ------- MFMA flash attention: software-pipelined, no-max softmax, packed idx -------
__launch_bounds__(256)
__global__ void attn_kernel(const ushort* __restrict__ qhi, const ushort* __restrict__ qlo,
                            const ushort* __restrict__ khi, const ushort* __restrict__ klo,
                            const ushort* __restrict__ vT, const ushort* __restrict__ tabBf,
                            const unsigned* __restrict__ idxP,
                            float* __restrict__ pO, float* __restrict__ pL) {
  __shared__ __align__(16) ushort pbuf[4][16 * PBS];
  __shared__ ushort tbf[TAB + 3];
  int tid = threadIdx.x;
  int lane = tid & 63;
  int w = tid >> 6;
  int qb = blockIdx.x;
  int by = blockIdx.y;
  int s = by & 3, bh = by >> 2;
  int h = bh & (NHEADS - 1);

  for (int t = tid; t < TAB; t += 256) tbf[t] = tabBf[h * TAB + t];

  int g = lane >> 4, c = lane & 15;
  int q0 = qb * 64 + w * 16;
  size_t rowbase = (size_t)bh * NSEQ;

  short8 qh = *(const short8*)&qhi[(rowbase + q0 + c) * HDIM + g * 8];
  short8 ql = *(const short8*)&qlo[(rowbase + q0 + c) * HDIM + g * 8];
  __syncthreads();

  float Lp[4] = {0.f, 0.f, 0.f, 0.f};
  f32x4 o0 = {0.f, 0.f, 0.f, 0.f}, o1 = {0.f, 0.f, 0.f, 0.f};
  ushort* pb = pbuf[w];
  int m0 = s * MSP;

#define LOADK(MT, D0H, D0L, D1H, D1L, I0, I1, I2, I3) do {            \
    size_t ra_ = (rowbase + (MT) + c) * HDIM + g * 8;                 \
    D0H = *(const short8*)&khi[ra_];                                  \
    D0L = *(const short8*)&klo[ra_];                                  \
    D1H = *(const short8*)&khi[ra_ + 16 * HDIM];                      \
    D1L = *(const short8*)&klo[ra_ + 16 * HDIM];                      \
    size_t ib_ = ((size_t)(q0 + g * 4) * NCHUNK + ((MT) >> 5)) * 16 + c; \
    I0 = idxP[ib_];                                                   \
    I1 = idxP[ib_ + (size_t)NCHUNK * 16];                             \
    I2 = idxP[ib_ + (size_t)2 * NCHUNK * 16];                         \
    I3 = idxP[ib_ + (size_t)3 * NCHUNK * 16];                         \
  } while (0)

  short8 c0h, c0l, c1h, c1l;
  unsigned ip0, ip1, ip2, ip3;
  LOADK(m0, c0h, c0l, c1h, c1l, ip0, ip1, ip2, ip3);

  for (int mt = m0; mt < m0 + MSP; mt += 32) {
    int mtn = (mt + 32 < m0 + MSP) ? (mt + 32) : m0;
    short8 n0h, n0l, n1h, n1l;
    unsigned jp0, jp1, jp2, jp3;
    LOADK(mtn, n0h, n0l, n1h, n1l, jp0, jp1, jp2, jp3);   // prefetch next

    f32x4 s0 = {0.f, 0.f, 0.f, 0.f}, s1 = {0.f, 0.f, 0.f, 0.f};
    s0 = MFMA16(qh, c0h, s0);
    s1 = MFMA16(qh, c1h, s1);
    s0 = MFMA16(ql, c0h, s0);
    s1 = MFMA16(ql, c1h, s1);
    s0 = MFMA16(qh, c0l, s0);
    s1 = MFMA16(qh, c1l, s1);

    size_t va = ((size_t)(bh * HDIM + c)) * NSEQ + mt + g * 8;   // vT loads early
    short8 vf0 = *(const short8*)&vT[va];
    short8 vf1 = *(const short8*)&vT[va + 16 * NSEQ];

    unsigned ipr[4] = {ip0, ip1, ip2, ip3};
#pragma unroll
    for (int r = 0; r < 4; ++r) {
      int i0 = ipr[r] & 0xFFFF, i1 = ipr[r] >> 16;
      float p0 = __expf(s0[r] + bf2f(tbf[i0]));
      float p1 = __expf(s1[r] + bf2f(tbf[i1]));
      Lp[r] += p0 + p1;
      unsigned pk = (unsigned)f2bf(p0) | ((unsigned)f2bf(p1) << 16);
      *(unsigned*)&pb[(g * 4 + r) * PBS + 2 * c] = pk;
    }

    short4v pa = *(const short4v*)&pb[c * PBS + g * 8];
    short4v pbv = *(const short4v*)&pb[c * PBS + g * 8 + 4];
    short8 pf = __builtin_shufflevector(pa, pbv, 0, 1, 2, 3, 4, 5, 6, 7);

    o0 = MFMA16(pf, vf0, o0);
    o1 = MFMA16(pf, vf1, o1);

    c0h = n0h; c0l = n0l; c1h = n1h; c1l = n1l;
    ip0 = jp0; ip1 = jp1; ip2 = jp2; ip3 = jp3;
  }
#undef LOADK

#pragma unroll
  for (int r = 0; r < 4; ++r) {
    float l = Lp[r];
    l += __shfl_xor(l, 1);
    l += __shfl_xor(l, 2);
    l += __shfl_xor(l, 4);
    l += __shfl_xor(l, 8);
    Lp[r] = l;
  }
  size_t prow0 = (size_t)s * RTOT + rowbase + q0;
#pragma unroll
  for (int r = 0; r < 4; ++r) {
    size_t pr = prow0 + g * 4 + r;
    pO[pr * HDIM + c]      = o0[r];
    pO[pr * HDIM + 16 + c] = o1[r];
    if (c == 0) pL[pr] = Lp[r];
  }
}

// ------- merge splits (coalesced: lane = channel), emit split-bf16 ao -------
__global__ void merge_kernel(const float* __restrict__ pO, const float* __restrict__ pL,
                             ushort* __restrict__ aoh, ushort* __restrict__ aol) {
  int t = threadIdx.x;
  int r = blockIdx.x * 8 + (t >> 5);
  int i = t & 31;
  float L = 0.f;
#pragma unroll
  for (int sp = 0; sp < SPLITS; ++sp) L += pL[(size_t)sp * RTOT + r];
  float inv = 1.f / L;
  float acc = 0.f;
#pragma unroll
  for (int sp = 0; sp < SPLITS; ++sp) acc += pO[((size_t)sp * RTOT + r) * HDIM + i];
  float v = acc * inv;
  int n = r % NSEQ; int bh = r / NSEQ; int h = bh & (NHEADS - 1); int b = bh >> 3;
  size_t dst = (size_t)(b * NSEQ + n) * DIMC + h * HDIM + i;
  ushort hh = f2bf(v);
  aoh[dst] = hh;
  aol[dst] = f2bf(v - bf2f(hh));
}

// ------- split-bf16 MFMA GEMM (proj): C[M,Nn] = A@W^T + bias -------
__launch_bounds__(256)
__global__ void gemm_mfma(const ushort* __restrict__ Ah, const ushort* __restrict__ Al,
                          const ushort* __restrict__ Bh, const ushort* __restrict__ Bl,
                          const float* __restrict__ bias, float* __restrict__ C,
                          int Nn, int K) {
  int tid = threadIdx.x;
  int lane = tid & 63;
  int w = tid >> 6;
  int g = lane >> 4, c = lane & 15;
  int n0 = blockIdx.x * 64;
  int m0 = blockIdx.y * 64 + w * 16;
  f32x4 acc[4] = {{0,0,0,0},{0,0,0,0},{0,0,0,0},{0,0,0,0}};
#pragma unroll 2
  for (int k0 = 0; k0 < K; k0 += 32) {
    short8 ah = *(const short8*)&Ah[(size_t)(m0 + c) * K + k0 + g * 8];
    short8 al = *(const short8*)&Al[(size_t)(m0 + c) * K + k0 + g * 8];
#pragma unroll
    for (int nt = 0; nt < 4; ++nt) {
      short8 bh = *(const short8*)&Bh[(size_t)(n0 + nt * 16 + c) * K + k0 + g * 8];
      short8 bl = *(const short8*)&Bl[(size_t)(n0 + nt * 16 + c) * K + k0 + g * 8];
      acc[nt] = MFMA16(ah, bh, acc[nt]);
      acc[nt] = MFMA16(al, bh, acc[nt]);
      acc[nt] = MFMA16(ah, bl, acc[nt]);
    }
  }
#pragma unroll
  for (int nt = 0; nt < 4; ++nt) {
    float bv = bias[n0 + nt * 16 + c];
#pragma unroll
    for (int r = 0; r < 4; ++r) {
      C[(size_t)(m0 + g * 4 + r) * Nn + n0 + nt * 16 + c] = acc[nt][r] + bv;
    }
  }
}

extern "C" void kernel_launch(void* const* d_in, const int* in_sizes, int n_in,
                              void* d_out, int out_size, void* d_ws, size_t ws_size,
                              hipStream_t stream) {
  const float* x    = (const float*)d_in[0];
  const int*   idx  = (const int*)d_in[1];
  const float* tbl  = (const float*)d_in[2];
  const float* sls  = (const float*)d_in[3];
  const float* Wqkv = (const float*)d_in[5];
  const float* bqkv = (const float*)d_in[6];
  const float* temp = (const float*)d_in[7];
  const float* qe   = (const float*)d_in[8];
  const float* Wp   = (const float*)d_in[9];
  const float* bp   = (const float*)d_in[10];
  const float* W1   = (const float*)d_in[11];
  const float* b1   = (const float*)d_in[12];
  const float* W2   = (const float*)d_in[13];
  const float* b2   = (const float*)d_in[14];

  float* ws   = (float*)d_ws;
  float* pO   = ws;                        // 4,718,592 f
  float* pL   = pO + 4718592;              // 147,456 f
  unsigned* idxP = (unsigned*)(pL + 147456);   // 2,654,208 u32
  ushort* u   = (ushort*)(idxP + IDXP_ELEMS);
  ushort* qhi = u;                u += (size_t)RTOT * HDIM;
  ushort* qlo = u;                u += (size_t)RTOT * HDIM;
  ushort* khi = u;                u += (size_t)RTOT * HDIM;
  ushort* klo = u;                u += (size_t)RTOT * HDIM;
  ushort* vT  = u;                u += (size_t)RTOT * HDIM;
  ushort* xh  = u;                u += NX;
  ushort* xl  = u;                u += NX;
  ushort* wqh = u;                u += NWQ;
  ushort* wql = u;                u += NWQ;
  ushort* wph = u;                u += NWP;
  ushort* wpl = u;                u += NWP;
  ushort* aoh = u;                u += (size_t)RTOT * HDIM;
  ushort* aol = u;                u += (size_t)RTOT * HDIM;
  ushort* tabBf = u;              u += 72256;   // NHEADS*TAB = 72,200
  float* out  = (float*)d_out;

  setup_kernel<<<dim3(CPB_BLOCKS + SPLIT_BLOCKS + IDXP_BLOCKS), dim3(256), 0, stream>>>(
      x, Wqkv, Wp, idx, tbl, W1, b1, W2, b2,
      xh, xl, wqh, wql, wph, wpl, idxP, tabBf);
  gemm_qkv<<<dim3(12, 72), dim3(256), 0, stream>>>(
      xh, xl, wqh, wql, bqkv, temp, sls, qe, qhi, qlo, khi, klo, vT);
  attn_kernel<<<dim3(NSEQ / 64, BB * NHEADS * SPLITS), dim3(256), 0, stream>>>(
      qhi, qlo, khi, klo, vT, tabBf, idxP, pO, pL);
  merge_kernel<<<dim3(RTOT / 8), dim3(256), 0, stream>>>(pO, pL, aoh, aol);
  gemm_mfma<<<dim3(4, 72), dim3(256), 0, stream>>>(aoh, aol, wph, wpl, bp, out, DIMC, DIMC);
}

// Round 8
// 231.885 us; speedup vs baseline: 1.4114x; 1.1262x over previous
//
#include <hip/hip_runtime.h>
#include <math.h>

#define DIMC 256
#define NHEADS 8
#define HDIM 32
#define CPBH 512
#define BB 2
#define NSEQ 2304
#define TAB 9025
#define RTOT (BB*NHEADS*NSEQ)      // 36864
#define SPLITS 4
#define MSP (NSEQ/SPLITS)          // 576 m per split
#define PBS 36                     // pbuf row stride in u16
#define NCHUNK (NSEQ/32)           // 72
#define LOG2E 1.44269504088896340736f

#define NX  (BB*NSEQ*DIMC)         // 1,179,648
#define NWQ (3*DIMC*DIMC)          // 196,608
#define NWP (DIMC*DIMC)            // 65,536

#define SPLIT_BLOCKS ((NX + NWQ + NWP) / 256)          // 5632
#define IDXP_ELEMS   (NSEQ * NCHUNK * 16)              // 2,654,208
#define IDXP_BLOCKS  (IDXP_ELEMS / 256)                // 10368
#define CPB_BLOCKS   ((TAB + 63) / 64)                 // 142

typedef unsigned short ushort;
typedef __attribute__((ext_vector_type(8))) short short8;
typedef __attribute__((ext_vector_type(4))) short short4v;
typedef __attribute__((ext_vector_type(4))) float f32x4;

#define MFMA16(a,b,c) __builtin_amdgcn_mfma_f32_16x16x32_bf16((a),(b),(c),0,0,0)

__device__ __forceinline__ ushort f2bf(float x) {          // RNE fp32->bf16
  unsigned u = __float_as_uint(x);
  u += 0x7FFFu + ((u >> 16) & 1u);
  return (ushort)(u >> 16);
}
__device__ __forceinline__ float bf2f(ushort b) {
  return __uint_as_float(((unsigned)b) << 16);
}
__device__ __forceinline__ float fexp2(float x) {
#if defined(__has_builtin)
#if __has_builtin(__builtin_amdgcn_exp2f)
  return __builtin_amdgcn_exp2f(x);
#else
  return exp2f(x);
#endif
#else
  return exp2f(x);
#endif
}
// pack two fp32 -> (trunc-bf16 pair) in one v_perm; also return the truncated floats
__device__ __forceinline__ unsigned pack_trunc(float p0, float p1, float* t0, float* t1) {
  unsigned u0 = __float_as_uint(p0), u1 = __float_as_uint(p1);
  *t0 = __uint_as_float(u0 & 0xFFFF0000u);
  *t1 = __uint_as_float(u1 & 0xFFFF0000u);
  return __builtin_amdgcn_perm(u1, u0, 0x07060302u);  // {u1.b3,u1.b2,u0.b3,u0.b2}
}

// ------- setup: CPB MLP (LDS-tiled, blocks FIRST) + split planes + idx pair-pack -------
__global__ void setup_kernel(const float* __restrict__ x, const float* __restrict__ wq,
                             const float* __restrict__ wp, const int* __restrict__ idx,
                             const float* __restrict__ tbl, const float* __restrict__ W1,
                             const float* __restrict__ b1, const float* __restrict__ W2,
                             const float* __restrict__ b2,
                             ushort* __restrict__ xh, ushort* __restrict__ xl,
                             ushort* __restrict__ wqh, ushort* __restrict__ wql,
                             ushort* __restrict__ wph, ushort* __restrict__ wpl,
                             unsigned* __restrict__ idxP, ushort* __restrict__ tabBf) {
  __shared__ float w1b[CPBH * 4];
  __shared__ float w2t[CPBH * NHEADS];
  __shared__ float part[4][64][NHEADS];
  int blk = blockIdx.x;
  int tid = threadIdx.x;
  if (blk < CPB_BLOCKS) {
    for (int i = tid; i < CPBH; i += 256) {
      w1b[i * 4 + 0] = W1[2 * i];
      w1b[i * 4 + 1] = W1[2 * i + 1];
      w1b[i * 4 + 2] = b1[i];
      w1b[i * 4 + 3] = 0.f;
    }
    for (int i = tid; i < CPBH * NHEADS; i += 256)
      w2t[(i & (CPBH - 1)) * NHEADS + (i >> 9)] = W2[i];
    int tl = tid & 63, jc = tid >> 6;
    int t = blk * 64 + tl;
    bool valid = t < TAB;
    float c0 = 0.f, c1 = 0.f;
    if (valid) { c0 = tbl[2 * t]; c1 = tbl[2 * t + 1]; }
    __syncthreads();
    float acc[NHEADS];
#pragma unroll
    for (int h = 0; h < NHEADS; ++h) acc[h] = 0.f;
    for (int j = jc * 128; j < jc * 128 + 128; ++j) {
      float4 wv = *(const float4*)&w1b[j * 4];
      float hid = fmaxf(fmaf(c0, wv.x, fmaf(c1, wv.y, wv.z)), 0.f);
      float4 wa = *(const float4*)&w2t[j * NHEADS];
      float4 wb = *(const float4*)&w2t[j * NHEADS + 4];
      acc[0] = fmaf(hid, wa.x, acc[0]);
      acc[1] = fmaf(hid, wa.y, acc[1]);
      acc[2] = fmaf(hid, wa.z, acc[2]);
      acc[3] = fmaf(hid, wa.w, acc[3]);
      acc[4] = fmaf(hid, wb.x, acc[4]);
      acc[5] = fmaf(hid, wb.y, acc[5]);
      acc[6] = fmaf(hid, wb.z, acc[6]);
      acc[7] = fmaf(hid, wb.w, acc[7]);
    }
#pragma unroll
    for (int h = 0; h < NHEADS; ++h) part[jc][tl][h] = acc[h];
    __syncthreads();
    if (jc == 0 && valid) {
#pragma unroll
      for (int h = 0; h < NHEADS; ++h) {
        float s = part[0][tl][h] + part[1][tl][h] + part[2][tl][h] + part[3][tl][h] + b2[h];
        tabBf[h * TAB + t] = f2bf(s * LOG2E);   // bias pre-scaled by log2(e)
      }
    }
  } else if (blk < CPB_BLOCKS + SPLIT_BLOCKS) {
    int i = (blk - CPB_BLOCKS) * 256 + tid;
    const float* src; ushort *hi, *lo; int j;
    if (i < NX)            { src = x;  hi = xh;  lo = xl;  j = i; }
    else if (i < NX + NWQ) { src = wq; hi = wqh; lo = wql; j = i - NX; }
    else                   { src = wp; hi = wph; lo = wpl; j = i - NX - NWQ; }
    float v = src[j];
    ushort h = f2bf(v);
    hi[j] = h;
    lo[j] = f2bf(v - bf2f(h));
  } else {
    int e = (blk - CPB_BLOCKS - SPLIT_BLOCKS) * 256 + tid;
    int cc = e & 15; int ch = (e >> 4) % NCHUNK; int n = e / (16 * NCHUNK);
    int mbase = ch * 32 + cc;
    unsigned lo = (unsigned)idx[(size_t)n * NSEQ + mbase];
    unsigned hi = (unsigned)idx[(size_t)n * NSEQ + mbase + 16];
    idxP[e] = lo | (hi << 16);
  }
}

// ------- fused QKV GEMM + norm/scale/split + V transpose -------
__launch_bounds__(256)
__global__ void gemm_qkv(const ushort* __restrict__ Ah, const ushort* __restrict__ Al,
                         const ushort* __restrict__ Bh, const ushort* __restrict__ Bl,
                         const float* __restrict__ bias, const float* __restrict__ temp,
                         const float* __restrict__ sls, const float* __restrict__ qe,
                         ushort* __restrict__ qhi, ushort* __restrict__ qlo,
                         ushort* __restrict__ khi, ushort* __restrict__ klo,
                         ushort* __restrict__ vT) {
  __shared__ float vbuf[64][65];
  int tid = threadIdx.x;
  int lane = tid & 63, w = tid >> 6;
  int g = lane >> 4, c = lane & 15;
  int n0 = blockIdx.x * 64, m0 = blockIdx.y * 64;
  int mw = m0 + w * 16;
  const int K = DIMC;
  f32x4 acc[4] = {{0,0,0,0},{0,0,0,0},{0,0,0,0},{0,0,0,0}};
#pragma unroll 2
  for (int k0 = 0; k0 < K; k0 += 32) {
    short8 ah = *(const short8*)&Ah[(size_t)(mw + c) * K + k0 + g * 8];
    short8 al = *(const short8*)&Al[(size_t)(mw + c) * K + k0 + g * 8];
#pragma unroll
    for (int nt = 0; nt < 4; ++nt) {
      short8 bh = *(const short8*)&Bh[(size_t)(n0 + nt * 16 + c) * K + k0 + g * 8];
      short8 bl = *(const short8*)&Bl[(size_t)(n0 + nt * 16 + c) * K + k0 + g * 8];
      acc[nt] = MFMA16(ah, bh, acc[nt]);
      acc[nt] = MFMA16(al, bh, acc[nt]);
      acc[nt] = MFMA16(ah, bl, acc[nt]);
    }
  }
#pragma unroll
  for (int nt = 0; nt < 4; ++nt) {
    float bv = bias[n0 + nt * 16 + c];
#pragma unroll
    for (int r = 0; r < 4; ++r) acc[nt][r] += bv;
  }

  int b = (m0 >= NSEQ) ? 1 : 0;
  int nb = m0 - b * NSEQ;
  int sect = n0 >> 8;

  if (sect < 2) {
    int hloc = (n0 & 255) >> 5;
#pragma unroll
    for (int H = 0; H < 2; ++H) {
      int head = hloc + H;
#pragma unroll
      for (int r = 0; r < 4; ++r) {
        float ss = acc[2*H][r]*acc[2*H][r] + acc[2*H+1][r]*acc[2*H+1][r];
        ss += __shfl_xor(ss, 1);
        ss += __shfl_xor(ss, 2);
        ss += __shfl_xor(ss, 4);
        ss += __shfl_xor(ss, 8);
        float inv = 1.f / fmaxf(sqrtf(ss), 1e-12f);
        int n = nb + w * 16 + g * 4 + r;
        size_t orow = ((size_t)(b * NHEADS + head) * NSEQ + n) * HDIM;
#pragma unroll
        for (int half = 0; half < 2; ++half) {
          int nt = 2*H + half;
          int d = half * 16 + c;
          float val = acc[nt][r] * inv;
          if (sect == 0) {
            float scale = log1pf(expf(temp[head])) * sls[0] * LOG2E;  // log2e folded into q
            val = (val + qe[head * HDIM + d]) * scale;
            ushort hh = f2bf(val);
            qhi[orow + d] = hh;
            qlo[orow + d] = f2bf(val - bf2f(hh));
          } else {
            ushort hh = f2bf(val);
            khi[orow + d] = hh;
            klo[orow + d] = f2bf(val - bf2f(hh));
          }
        }
      }
    }
  } else {
#pragma unroll
    for (int nt = 0; nt < 4; ++nt)
#pragma unroll
      for (int r = 0; r < 4; ++r)
        vbuf[w * 16 + g * 4 + r][nt * 16 + c] = acc[nt][r];
    __syncthreads();
    int hbase = (n0 - 512) >> 5;
#pragma unroll
    for (int it = 0; it < 16; ++it) {
      int dloc = (tid >> 6) * 16 + it;
      int p = tid & 63;
      int pp = p & 31;
      int nsrc = (p & 32) + (pp & 1) * 16 + (pp >> 1);
      float v = vbuf[nsrc][dloc];
      int head = hbase + (dloc >> 5), d = dloc & 31;
      vT[((size_t)((b * NHEADS + head) * HDIM + d)) * NSEQ + nb + p] = f2bf(v);
    }
  }
}

// ------- MFMA flash attention: 2 q-tiles/wave, exp2 path, perm-pack, SPLITS=4 -------
__launch_bounds__(256)
__global__ void attn_kernel(const ushort* __restrict__ qhi, const ushort* __restrict__ qlo,
                            const ushort* __restrict__ khi, const ushort* __restrict__ klo,
                            const ushort* __restrict__ vT, const ushort* __restrict__ tabBf,
                            const unsigned* __restrict__ idxP,
                            float* __restrict__ pO, float* __restrict__ pL) {
  __shared__ __align__(16) ushort pbuf[8][16 * PBS];   // 4 waves x 2 tiles
  __shared__ ushort tbf[TAB + 3];
  int tid = threadIdx.x;
  int lane = tid & 63;
  int w = tid >> 6;
  int qb = blockIdx.x;                  // 0..17 : 128-q-row tile
  int by = blockIdx.y;                  // 0..63
  int s = by & 3, bh = by >> 2;
  int h = bh & (NHEADS - 1);

  for (int t = tid; t < TAB; t += 256) tbf[t] = tabBf[h * TAB + t];

  int g = lane >> 4, c = lane & 15;
  int q0 = qb * 128 + w * 16;           // tile A rows
  int q1 = q0 + 64;                     // tile B rows
  size_t rowbase = (size_t)bh * NSEQ;

  short8 qha = *(const short8*)&qhi[(rowbase + q0 + c) * HDIM + g * 8];
  short8 qla = *(const short8*)&qlo[(rowbase + q0 + c) * HDIM + g * 8];
  short8 qhb = *(const short8*)&qhi[(rowbase + q1 + c) * HDIM + g * 8];
  short8 qlb = *(const short8*)&qlo[(rowbase + q1 + c) * HDIM + g * 8];
  __syncthreads();

  float La[4] = {0.f, 0.f, 0.f, 0.f}, Lb[4] = {0.f, 0.f, 0.f, 0.f};
  f32x4 oa0 = {0,0,0,0}, oa1 = {0,0,0,0}, ob0 = {0,0,0,0}, ob1 = {0,0,0,0};
  ushort* pba = pbuf[w * 2];
  ushort* pbb = pbuf[w * 2 + 1];
  int m0 = s * MSP;

  short8 c0h, c0l, c1h, c1l;
  {
    size_t ra = (rowbase + m0 + c) * HDIM + g * 8;
    c0h = *(const short8*)&khi[ra];
    c0l = *(const short8*)&klo[ra];
    c1h = *(const short8*)&khi[ra + 16 * HDIM];
    c1l = *(const short8*)&klo[ra + 16 * HDIM];
  }

  for (int mt = m0; mt < m0 + MSP; mt += 32) {
    int mtn = (mt + 32 < m0 + MSP) ? (mt + 32) : m0;
    short8 n0h, n0l, n1h, n1l;
    {
      size_t ra = (rowbase + mtn + c) * HDIM + g * 8;
      n0h = *(const short8*)&khi[ra];
      n0l = *(const short8*)&klo[ra];
      n1h = *(const short8*)&khi[ra + 16 * HDIM];
      n1l = *(const short8*)&klo[ra + 16 * HDIM];
    }

    // idx pairs, both tiles (coalesced dwords; L2-hot)
    size_t iba = ((size_t)(q0 + g * 4) * NCHUNK + (mt >> 5)) * 16 + c;
    unsigned ia0 = idxP[iba];
    unsigned ia1 = idxP[iba + (size_t)NCHUNK * 16];
    unsigned ia2 = idxP[iba + (size_t)2 * NCHUNK * 16];
    unsigned ia3 = idxP[iba + (size_t)3 * NCHUNK * 16];
    size_t ibb = ((size_t)(q1 + g * 4) * NCHUNK + (mt >> 5)) * 16 + c;
    unsigned ib0 = idxP[ibb];
    unsigned ib1 = idxP[ibb + (size_t)NCHUNK * 16];
    unsigned ib2 = idxP[ibb + (size_t)2 * NCHUNK * 16];
    unsigned ib3 = idxP[ibb + (size_t)3 * NCHUNK * 16];

    // QK^T for both q-tiles (K-frags shared)
    f32x4 sa0 = {0,0,0,0}, sa1 = {0,0,0,0}, sb0 = {0,0,0,0}, sb1 = {0,0,0,0};
    sa0 = MFMA16(qha, c0h, sa0);
    sb0 = MFMA16(qhb, c0h, sb0);
    sa1 = MFMA16(qha, c1h, sa1);
    sb1 = MFMA16(qhb, c1h, sb1);
    sa0 = MFMA16(qla, c0h, sa0);
    sb0 = MFMA16(qlb, c0h, sb0);
    sa1 = MFMA16(qla, c1h, sa1);
    sb1 = MFMA16(qlb, c1h, sb1);
    sa0 = MFMA16(qha, c0l, sa0);
    sb0 = MFMA16(qhb, c0l, sb0);
    sa1 = MFMA16(qha, c1l, sa1);
    sb1 = MFMA16(qhb, c1l, sb1);

    size_t va = ((size_t)(bh * HDIM + c)) * NSEQ + mt + g * 8;   // vT shared
    short8 vf0 = *(const short8*)&vT[va];
    short8 vf1 = *(const short8*)&vT[va + 16 * NSEQ];

    unsigned ipa[4] = {ia0, ia1, ia2, ia3};
    unsigned ipb[4] = {ib0, ib1, ib2, ib3};
#pragma unroll
    for (int r = 0; r < 4; ++r) {
      float p0 = fexp2(sa0[r] + bf2f((ushort)(ipa[r] & 0xFFFF)));
      float p1 = fexp2(sa1[r] + bf2f((ushort)(ipa[r] >> 16)) );
      // NOTE: ipa holds table indices, not bias values — gather below
      (void)p0; (void)p1;
      break;
    }
    // gather bias from LDS and do exp2/pack (tile A then tile B)
#pragma unroll
    for (int r = 0; r < 4; ++r) {
      int i0 = ipa[r] & 0xFFFF, i1 = ipa[r] >> 16;
      float p0 = fexp2(sa0[r] + bf2f(tbf[i0]));
      float p1 = fexp2(sa1[r] + bf2f(tbf[i1]));
      float t0, t1;
      unsigned pk = pack_trunc(p0, p1, &t0, &t1);
      La[r] += t0 + t1;
      *(unsigned*)&pba[(g * 4 + r) * PBS + 2 * c] = pk;
    }
#pragma unroll
    for (int r = 0; r < 4; ++r) {
      int i0 = ipb[r] & 0xFFFF, i1 = ipb[r] >> 16;
      float p0 = fexp2(sb0[r] + bf2f(tbf[i0]));
      float p1 = fexp2(sb1[r] + bf2f(tbf[i1]));
      float t0, t1;
      unsigned pk = pack_trunc(p0, p1, &t0, &t1);
      Lb[r] += t0 + t1;
      *(unsigned*)&pbb[(g * 4 + r) * PBS + 2 * c] = pk;
    }

    // C->A layout via LDS (compiler inserts DS waits)
    short4v paA = *(const short4v*)&pba[c * PBS + g * 8];
    short4v paB = *(const short4v*)&pba[c * PBS + g * 8 + 4];
    short8 pfa = __builtin_shufflevector(paA, paB, 0, 1, 2, 3, 4, 5, 6, 7);
    short4v pbA = *(const short4v*)&pbb[c * PBS + g * 8];
    short4v pbB = *(const short4v*)&pbb[c * PBS + g * 8 + 4];
    short8 pfb = __builtin_shufflevector(pbA, pbB, 0, 1, 2, 3, 4, 5, 6, 7);

    oa0 = MFMA16(pfa, vf0, oa0);
    oa1 = MFMA16(pfa, vf1, oa1);
    ob0 = MFMA16(pfb, vf0, ob0);
    ob1 = MFMA16(pfb, vf1, ob1);

    c0h = n0h; c0l = n0l; c1h = n1h; c1l = n1l;
  }

#pragma unroll
  for (int r = 0; r < 4; ++r) {
    float la = La[r], lb = Lb[r];
    la += __shfl_xor(la, 1); lb += __shfl_xor(lb, 1);
    la += __shfl_xor(la, 2); lb += __shfl_xor(lb, 2);
    la += __shfl_xor(la, 4); lb += __shfl_xor(lb, 4);
    la += __shfl_xor(la, 8); lb += __shfl_xor(lb, 8);
    La[r] = la; Lb[r] = lb;
  }
  size_t prow0 = (size_t)s * RTOT + rowbase;
#pragma unroll
  for (int r = 0; r < 4; ++r) {
    size_t pra = prow0 + q0 + g * 4 + r;
    pO[pra * HDIM + c]      = oa0[r];
    pO[pra * HDIM + 16 + c] = oa1[r];
    size_t prb = prow0 + q1 + g * 4 + r;
    pO[prb * HDIM + c]      = ob0[r];
    pO[prb * HDIM + 16 + c] = ob1[r];
    if (c == 0) { pL[pra] = La[r]; pL[prb] = Lb[r]; }
  }
}

// ------- merge splits (coalesced: lane = channel), emit split-bf16 ao -------
__global__ void merge_kernel(const float* __restrict__ pO, const float* __restrict__ pL,
                             ushort* __restrict__ aoh, ushort* __restrict__ aol) {
  int t = threadIdx.x;
  int r = blockIdx.x * 8 + (t >> 5);
  int i = t & 31;
  float L = 0.f;
#pragma unroll
  for (int sp = 0; sp < SPLITS; ++sp) L += pL[(size_t)sp * RTOT + r];
  float inv = 1.f / L;
  float acc = 0.f;
#pragma unroll
  for (int sp = 0; sp < SPLITS; ++sp) acc += pO[((size_t)sp * RTOT + r) * HDIM + i];
  float v = acc * inv;
  int n = r % NSEQ; int bh = r / NSEQ; int h = bh & (NHEADS - 1); int b = bh >> 3;
  size_t dst = (size_t)(b * NSEQ + n) * DIMC + h * HDIM + i;
  ushort hh = f2bf(v);
  aoh[dst] = hh;
  aol[dst] = f2bf(v - bf2f(hh));
}

// ------- split-bf16 MFMA GEMM (proj) -------
__launch_bounds__(256)
__global__ void gemm_mfma(const ushort* __restrict__ Ah, const ushort* __restrict__ Al,
                          const ushort* __restrict__ Bh, const ushort* __restrict__ Bl,
                          const float* __restrict__ bias, float* __restrict__ C,
                          int Nn, int K) {
  int tid = threadIdx.x;
  int lane = tid & 63;
  int w = tid >> 6;
  int g = lane >> 4, c = lane & 15;
  int n0 = blockIdx.x * 64;
  int m0 = blockIdx.y * 64 + w * 16;
  f32x4 acc[4] = {{0,0,0,0},{0,0,0,0},{0,0,0,0},{0,0,0,0}};
#pragma unroll 2
  for (int k0 = 0; k0 < K; k0 += 32) {
    short8 ah = *(const short8*)&Ah[(size_t)(m0 + c) * K + k0 + g * 8];
    short8 al = *(const short8*)&Al[(size_t)(m0 + c) * K + k0 + g * 8];
#pragma unroll
    for (int nt = 0; nt < 4; ++nt) {
      short8 bh = *(const short8*)&Bh[(size_t)(n0 + nt * 16 + c) * K + k0 + g * 8];
      short8 bl = *(const short8*)&Bl[(size_t)(n0 + nt * 16 + c) * K + k0 + g * 8];
      acc[nt] = MFMA16(ah, bh, acc[nt]);
      acc[nt] = MFMA16(al, bh, acc[nt]);
      acc[nt] = MFMA16(ah, bl, acc[nt]);
    }
  }
#pragma unroll
  for (int nt = 0; nt < 4; ++nt) {
    float bv = bias[n0 + nt * 16 + c];
#pragma unroll
    for (int r = 0; r < 4; ++r) {
      C[(size_t)(m0 + g * 4 + r) * Nn + n0 + nt * 16 + c] = acc[nt][r] + bv;
    }
  }
}

extern "C" void kernel_launch(void* const* d_in, const int* in_sizes, int n_in,
                              void* d_out, int out_size, void* d_ws, size_t ws_size,
                              hipStream_t stream) {
  const float* x    = (const float*)d_in[0];
  const int*   idx  = (const int*)d_in[1];
  const float* tbl  = (const float*)d_in[2];
  const float* sls  = (const float*)d_in[3];
  const float* Wqkv = (const float*)d_in[5];
  const float* bqkv = (const float*)d_in[6];
  const float* temp = (const float*)d_in[7];
  const float* qe   = (const float*)d_in[8];
  const float* Wp   = (const float*)d_in[9];
  const float* bp   = (const float*)d_in[10];
  const float* W1   = (const float*)d_in[11];
  const float* b1   = (const float*)d_in[12];
  const float* W2   = (const float*)d_in[13];
  const float* b2   = (const float*)d_in[14];

  float* ws   = (float*)d_ws;
  float* pO   = ws;                        // 4,718,592 f
  float* pL   = pO + 4718592;              // 147,456 f
  unsigned* idxP = (unsigned*)(pL + 147456);   // 2,654,208 u32
  ushort* u   = (ushort*)(idxP + IDXP_ELEMS);
  ushort* qhi = u;                u += (size_t)RTOT * HDIM;
  ushort* qlo = u;                u += (size_t)RTOT * HDIM;
  ushort* khi = u;                u += (size_t)RTOT * HDIM;
  ushort* klo = u;                u += (size_t)RTOT * HDIM;
  ushort* vT  = u;                u += (size_t)RTOT * HDIM;
  ushort* xh  = u;                u += NX;
  ushort* xl  = u;                u += NX;
  ushort* wqh = u;                u += NWQ;
  ushort* wql = u;                u += NWQ;
  ushort* wph = u;                u += NWP;
  ushort* wpl = u;                u += NWP;
  ushort* aoh = u;                u += (size_t)RTOT * HDIM;
  ushort* aol = u;                u += (size_t)RTOT * HDIM;
  ushort* tabBf = u;              u += 72256;
  float* out  = (float*)d_out;

  setup_kernel<<<dim3(CPB_BLOCKS + SPLIT_BLOCKS + IDXP_BLOCKS), dim3(256), 0, stream>>>(
      x, Wqkv, Wp, idx, tbl, W1, b1, W2, b2,
      xh, xl, wqh, wql, wph, wpl, idxP, tabBf);
  gemm_qkv<<<dim3(12, 72), dim3(256), 0, stream>>>(
      xh, xl, wqh, wql, bqkv, temp, sls, qe, qhi, qlo, khi, klo, vT);
  attn_kernel<<<dim3(NSEQ / 128, BB * NHEADS * SPLITS), dim3(256), 0, stream>>>(
      qhi, qlo, khi, klo, vT, tabBf, idxP, pO, pL);
  merge_kernel<<<dim3(RTOT / 8), dim3(256), 0, stream>>>(pO, pL, aoh, aol);
  gemm_mfma<<<dim3(4, 72), dim3(256), 0, stream>>>(aoh, aol, wph, wpl, bp, out, DIMC, DIMC);
}